// Round 7
// baseline (71.004 us; speedup 1.0000x reference)
//
#include <hip/hip_runtime.h>
#include <math.h>

#define NB     24
#define FBIN   512
#define ROWS   (32*1200)
#define GRID   2048
#define BLK    256
#define WPB    4
#define NWAVES (GRID*WPB)    // 8192 waves; 4-5 rows each
#define SLOTS  20            // stride 80 B -> 16B-aligned b128 reads

__device__ __constant__ int   c_off[NB+1] = {0,3,6,9,12,16,20,24,29,34,40,47,55,64,74,86,100,118,140,169,204,246,304,384,512};
__device__ __constant__ float c_k[NB]     = {3,3,3,3,4,4,4,5,5,6,7,8,9,10,12,14,18,22,29,35,42,58,80,128};

// ---------------- Kernel A: per-row band thresholds t[row][24] ----------------
__global__ __launch_bounds__(BLK) void pe_bands(const float* __restrict__ lm,
                                                const float* __restrict__ S,
                                                float* __restrict__ t_out)
{
    __shared__ float s_slot[WPB][NB*SLOTS];
    __shared__ float s_psum[WPB][NB];

    const int tid  = threadIdx.x;
    const int w    = tid >> 6;
    const int lane = tid & 63;
    float* const slot = s_slot[w];
    float* const psum = s_psum[w];

    for (int i = lane; i < NB*SLOTS; i += 64) slot[i] = 0.f;   // pad stays 0 forever

    // per-lane metadata
    const int bin0 = lane * 8;
    int waddr[8];
    #pragma unroll
    for (int j = 0; j < 8; ++j) {
        const int binj = bin0 + j;
        int b = 0;
        for (int q = 0; q < NB; ++q) if (binj >= c_off[q+1]) b++;
        waddr[j] = b*SLOTS + (lane - (c_off[b] >> 3));
    }
    // S column for my band (lanes 0-23 meaningful) + invcol, in registers
    const int cl = (lane < NB) ? lane : 0;
    float Sreg[NB];
    float colsum = 1e-8f;
    #pragma unroll
    for (int i = 0; i < NB; ++i) { Sreg[i] = S[i*NB + cl]; colsum += Sreg[i]; }
    const float invcol = 1.0f / colsum;

    const int gw = blockIdx.x * WPB + w;
    size_t base = (size_t)gw * FBIN + bin0;
    const size_t step = (size_t)NWAVES * FBIN;

    float4 L0{}, L1{};
    if (gw < ROWS) { L0 = *(const float4*)(lm + base); L1 = *(const float4*)(lm + base + 4); }

    for (int row = gw; row < ROWS; row += NWAVES) {
        const float lmv[8] = {L0.x,L0.y,L0.z,L0.w,L1.x,L1.y,L1.z,L1.w};
        float sp[8];
        #pragma unroll
        for (int j = 0; j < 8; ++j)
            sp[j] = __builtin_amdgcn_exp2f(fminf(fmaxf(lmv[j], -1000.f), 10.f) * 1.44269504f);

        // segmented per-band partials -> per-wave LDS slots
        {
            float ps = sp[0]; int wa = waddr[0];
            #pragma unroll
            for (int j = 1; j < 8; ++j) {
                if (waddr[j] == wa) ps += sp[j];
                else { slot[wa] = ps; wa = waddr[j]; ps = sp[j]; }
            }
            slot[wa] = ps;
        }

        // prefetch next row's lm
        float4 nL0{}, nL1{};
        if (row + NWAVES < ROWS) {
            nL0 = *(const float4*)(lm + base + step);
            nL1 = *(const float4*)(lm + base + step + 4);
        }

        asm volatile("s_waitcnt lgkmcnt(0)" ::: "memory");

        if (lane < NB) {
            const float4* sp4 = (const float4*)(slot + lane*SLOTS);
            float4 q0 = sp4[0], q1 = sp4[1], q2 = sp4[2], q3 = sp4[3], q4 = sp4[4];
            float s01 = (q0.x+q0.y)+(q0.z+q0.w);
            float s23 = (q1.x+q1.y)+(q1.z+q1.w);
            float s45 = (q2.x+q2.y)+(q2.z+q2.w);
            float s67 = (q3.x+q3.y)+(q3.z+q3.w);
            float s89 = (q4.x+q4.y)+(q4.z+q4.w);
            psum[lane] = ((s01+s23)+(s45+s67))+s89;
        }
        asm volatile("s_waitcnt lgkmcnt(0)" ::: "memory");

        if (lane < NB) {
            float c0 = 1e-8f, c1 = 0.f, c2 = 0.f, c3 = 0.f;
            #pragma unroll
            for (int i = 0; i < NB; i += 4) {
                c0 = fmaf(psum[i+0], Sreg[i+0], c0);
                c1 = fmaf(psum[i+1], Sreg[i+1], c1);
                c2 = fmaf(psum[i+2], Sreg[i+2], c2);
                c3 = fmaf(psum[i+3], Sreg[i+3], c3);
            }
            t_out[(size_t)row*NB + lane] = ((c0+c1)+(c2+c3)) * invcol;
        }
        asm volatile("s_waitcnt lgkmcnt(0)" ::: "memory");

        L0 = nL0; L1 = nL1;
        base += step;
    }
}

// ---------------- Kernel B: pure streaming per-bin entropy ----------------
__global__ __launch_bounds__(BLK) void pe_bins(const float* __restrict__ lm,
                                               const float* __restrict__ re,
                                               const float* __restrict__ im,
                                               const float* __restrict__ t_in,
                                               float* __restrict__ partial)
{
    const int tid  = threadIdx.x;
    const int w    = tid >> 6;
    const int lane = tid & 63;

    const int bin0 = lane * 8;
    int band[8];
    float tq[8], a4[8];
    #pragma unroll
    for (int j = 0; j < 8; ++j) {
        const int binj = bin0 + j;
        int b = 0;
        for (int q = 0; q < NB; ++q) if (binj >= c_off[q+1]) b++;
        band[j] = b;
        float z = (binj + 1) * 0.03125f;
        tq[j] = 3.64f*powf(z + 1e-6f, -0.8f)
              - 6.5f*expf(-0.6f*(z-3.3f)*(z-3.3f))
              + 1e-3f*z*z*z*z;
        a4[j] = 1.5f / c_k[b];            // 2/denom == rsqrt(a4 * t_bin); weight = a4/57600
    }

    const int gw = blockIdx.x * WPB + w;
    size_t base = (size_t)gw * FBIN + bin0;
    const size_t step = (size_t)NWAVES * FBIN;

    float4 L0{}, L1{}, R0{}, R1{}, I0{}, I1{};
    if (gw < ROWS) {
        L0 = *(const float4*)(lm + base); L1 = *(const float4*)(lm + base + 4);
        R0 = *(const float4*)(re + base); R1 = *(const float4*)(re + base + 4);
        I0 = *(const float4*)(im + base); I1 = *(const float4*)(im + base + 4);
    }

    float acc = 0.f;
    for (int row = gw; row < ROWS; row += NWAVES) {
        // current row's band thresholds (small, cache-resident)
        const float* trow = t_in + (size_t)row * NB;
        float tl[8];
        #pragma unroll
        for (int j = 0; j < 8; ++j) tl[j] = trow[band[j]];

        // prefetch next row (all three streams)
        float4 nL0{}, nL1{}, nR0{}, nR1{}, nI0{}, nI1{};
        if (row + NWAVES < ROWS) {
            const size_t nb = base + step;
            nL0 = *(const float4*)(lm + nb); nL1 = *(const float4*)(lm + nb + 4);
            nR0 = *(const float4*)(re + nb); nR1 = *(const float4*)(re + nb + 4);
            nI0 = *(const float4*)(im + nb); nI1 = *(const float4*)(im + nb + 4);
        }

        const float lmv[8] = {L0.x,L0.y,L0.z,L0.w,L1.x,L1.y,L1.z,L1.w};
        const float rv[8]  = {R0.x,R0.y,R0.z,R0.w,R1.x,R1.y,R1.z,R1.w};
        const float iv[8]  = {I0.x,I0.y,I0.z,I0.w,I1.x,I1.y,I1.z,I1.w};
        #pragma unroll
        for (int j = 0; j < 8; ++j) {
            const float sp = __builtin_amdgcn_exp2f(fminf(fmaxf(lmv[j], -1000.f), 10.f) * 1.44269504f);
            const float t  = fmaxf(tl[j], tq[j]);
            const float s  = __builtin_amdgcn_rsqf(a4[j] * t);
            const float u  = sp * s;
            const float per = __builtin_amdgcn_logf(fmaf(fabsf(rv[j]), u, 1.0f));
            const float pei = __builtin_amdgcn_logf(fmaf(fabsf(iv[j]), u, 1.0f));
            acc = fmaf(per + pei, a4[j], acc);
        }

        L0 = nL0; L1 = nL1; R0 = nR0; R1 = nR1; I0 = nI0; I1 = nI1;
        base += step;
    }

    #pragma unroll
    for (int o = 32; o > 0; o >>= 1) acc += __shfl_xor(acc, o, 64);
    if (lane == 0) partial[gw] = acc * (1.0f/57600.0f);
}

__global__ __launch_bounds__(256) void pe_final(const float* __restrict__ partial,
                                                float* __restrict__ out)
{
    __shared__ double sred[256];
    const int tid = threadIdx.x;
    double s = 0.0;
    for (int i = tid; i < NWAVES; i += 256) s += (double)partial[i];
    sred[tid] = s;
    __syncthreads();
    for (int k = 128; k > 0; k >>= 1) {
        if (tid < k) sred[tid] += sred[tid+k];
        __syncthreads();
    }
    if (tid == 0) out[0] = (float)(1.0 / (sred[0] + 1.0));
}

extern "C" void kernel_launch(void* const* d_in, const int* in_sizes, int n_in,
                              void* d_out, int out_size, void* d_ws, size_t ws_size,
                              hipStream_t stream) {
    const float* lm = (const float*)d_in[0];
    const float* re = (const float*)d_in[1];
    const float* im = (const float*)d_in[2];
    const float* S  = (const float*)d_in[3];
    float* t_ws    = (float*)d_ws;                 // ROWS*NB floats = 3.686 MB
    float* partial = t_ws + (size_t)ROWS * NB;     // NWAVES floats = 32 KB
    pe_bands<<<GRID, BLK, 0, stream>>>(lm, S, t_ws);
    pe_bins <<<GRID, BLK, 0, stream>>>(lm, re, im, t_ws, partial);
    pe_final<<<1, 256, 0, stream>>>(partial, (float*)d_out);
}

// Round 8
// 51.409 us; speedup vs baseline: 1.3812x; 1.3812x over previous
//
#include <hip/hip_runtime.h>
#include <math.h>

#define NB     24
#define FBIN   512
#define ROWS   (32*1200)
#define GRID   2048
#define BLK    256
#define WPB    4
#define NWAVES (GRID*WPB)    // 8192 waves; 4-5 rows each
#define SLOTS  20            // stride 80 B -> 16B-aligned b128 reads
#define LOG2E  1.44269504f

__device__ __constant__ int   c_off[NB+1] = {0,3,6,9,12,16,20,24,29,34,40,47,55,64,74,86,100,118,140,169,204,246,304,384,512};
__device__ __constant__ float c_k[NB]     = {3,3,3,3,4,4,4,5,5,6,7,8,9,10,12,14,18,22,29,35,42,58,80,128};

__global__ __launch_bounds__(BLK) void pe_main(const float* __restrict__ lm,
                                               const float* __restrict__ re,
                                               const float* __restrict__ im,
                                               const float* __restrict__ S,
                                               float* __restrict__ partial)
{
    __shared__ float s_slot[WPB][NB*SLOTS];   // 7.7 KB total

    const int tid  = threadIdx.x;
    const int w    = tid >> 6;
    const int lane = tid & 63;
    float* const slot = s_slot[w];

    for (int i = lane; i < NB*SLOTS; i += 64) slot[i] = 0.f;   // pad stays 0 forever

    // ---- per-lane row-invariant metadata (8 contiguous bins per lane) ----
    const int bin0 = lane * 8;
    int waddr[8], band4[8];
    float tq[8], a4[8];
    #pragma unroll
    for (int j = 0; j < 8; ++j) {
        const int binj = bin0 + j;
        int b = 0;
        for (int q = 0; q < NB; ++q) if (binj >= c_off[q+1]) b++;
        band4[j] = b << 2;
        waddr[j] = b*SLOTS + (lane - (c_off[b] >> 3));
        const float z = (binj + 1) * 0.03125f;
        tq[j] = 3.64f*__builtin_amdgcn_exp2f(-0.8f*__builtin_amdgcn_logf(z + 1e-6f))
              - 6.5f*__builtin_amdgcn_exp2f(-0.6f*LOG2E*(z-3.3f)*(z-3.3f))
              + 1e-3f*z*z*z*z;
        a4[j] = 1.5f / c_k[b];            // 2/denom == rsqrt(a4 * t_bin); weight = a4/57600
    }

    // S column for my band (lanes 0-23) + 1/(colsum+eps), in registers
    const int cl = (lane < NB) ? lane : 0;
    float Sreg[NB];
    float colsum = 1e-8f;
    #pragma unroll
    for (int i = 0; i < NB; ++i) { Sreg[i] = S[i*NB + cl]; colsum += Sreg[i]; }
    const float invcol = 1.0f / colsum;

    const int gw = blockIdx.x * WPB + w;
    size_t base = (size_t)gw * FBIN + bin0;
    const size_t step = (size_t)NWAVES * FBIN;

    float4 L0 = *(const float4*)(lm + base);
    float4 L1 = *(const float4*)(lm + base + 4);

    float acc = 0.f;
    for (int row = gw; row < ROWS; row += NWAVES) {
        // current row's re/im: consumed only in the last phase (latency covered)
        const float4 R0 = *(const float4*)(re + base);
        const float4 R1 = *(const float4*)(re + base + 4);
        const float4 I0 = *(const float4*)(im + base);
        const float4 I1 = *(const float4*)(im + base + 4);

        const float lmv[8] = {L0.x,L0.y,L0.z,L0.w,L1.x,L1.y,L1.z,L1.w};
        float sp[8];
        #pragma unroll
        for (int j = 0; j < 8; ++j)
            sp[j] = __builtin_amdgcn_exp2f(fminf(lmv[j], 10.f) * LOG2E);

        // branchless segmented stores: cumulative rewrite, last write per slot wins
        {
            float ps = sp[0];
            slot[waddr[0]] = ps;
            #pragma unroll
            for (int j = 1; j < 8; ++j) {
                ps = (waddr[j] == waddr[j-1]) ? ps + sp[j] : sp[j];
                slot[waddr[j]] = ps;
            }
        }

        // prefetch next row's lm (clamped uniform address; no zero-init)
        const size_t nb = base + ((row + NWAVES < ROWS) ? step : (size_t)0);
        const float4 nL0 = *(const float4*)(lm + nb);
        const float4 nL1 = *(const float4*)(lm + nb + 4);

        asm volatile("s_waitcnt lgkmcnt(0)" ::: "memory");   // stores visible to own wave

        // per-band sums: lanes 0-23 read their 5x b128 from zero-padded slots
        float psum_v = 0.f;
        if (lane < NB) {
            const float4* sp4 = (const float4*)(slot + lane*SLOTS);
            const float4 q0 = sp4[0], q1 = sp4[1], q2 = sp4[2], q3 = sp4[3], q4 = sp4[4];
            psum_v = ((((q0.x+q0.y)+(q0.z+q0.w)) + ((q1.x+q1.y)+(q1.z+q1.w)))
                   +  (((q2.x+q2.y)+(q2.z+q2.w)) + ((q3.x+q3.y)+(q3.z+q3.w))))
                   +   ((q4.x+q4.y)+(q4.z+q4.w));
        }

        // t = (psum@S + eps)/(colsum + eps); psum broadcast via readlane (SGPR operands)
        float tmine;
        {
            float c0 = 1e-8f, c1 = 0.f, c2 = 0.f, c3 = 0.f;
            #pragma unroll
            for (int i = 0; i < NB; i += 4) {
                const float p0 = __int_as_float(__builtin_amdgcn_readlane(__float_as_int(psum_v), i+0));
                const float p1 = __int_as_float(__builtin_amdgcn_readlane(__float_as_int(psum_v), i+1));
                const float p2 = __int_as_float(__builtin_amdgcn_readlane(__float_as_int(psum_v), i+2));
                const float p3 = __int_as_float(__builtin_amdgcn_readlane(__float_as_int(psum_v), i+3));
                c0 = fmaf(p0, Sreg[i+0], c0);
                c1 = fmaf(p1, Sreg[i+1], c1);
                c2 = fmaf(p2, Sreg[i+2], c2);
                c3 = fmaf(p3, Sreg[i+3], c3);
            }
            tmine = ((c0+c1)+(c2+c3)) * invcol;
        }

        // broadcast t[band] to every lane via bpermute (no LDS storage)
        float tb[8];
        #pragma unroll
        for (int j = 0; j < 8; ++j)
            tb[j] = __int_as_float(__builtin_amdgcn_ds_bpermute(band4[j], __float_as_int(tmine)));

        const float rv[8] = {R0.x,R0.y,R0.z,R0.w,R1.x,R1.y,R1.z,R1.w};
        const float iv[8] = {I0.x,I0.y,I0.z,I0.w,I1.x,I1.y,I1.z,I1.w};
        #pragma unroll
        for (int j = 0; j < 8; ++j) {
            const float t  = fmaxf(tb[j], tq[j]);
            const float s  = __builtin_amdgcn_rsqf(a4[j] * t);
            const float u  = sp[j] * s;
            const float pr = fmaf(fabsf(rv[j]), u, 1.0f);
            const float pi = fmaf(fabsf(iv[j]), u, 1.0f);
            acc = fmaf(__builtin_amdgcn_logf(pr * pi), a4[j], acc);   // log2(x*y)=log2x+log2y
        }

        // drain slot reads before next iteration's stores overwrite them
        asm volatile("s_waitcnt lgkmcnt(0)" ::: "memory");

        L0 = nL0; L1 = nL1;
        base += step;
    }

    #pragma unroll
    for (int o = 32; o > 0; o >>= 1) acc += __shfl_xor(acc, o, 64);
    if (lane == 0) partial[gw] = acc * (1.0f/57600.0f);
}

__global__ __launch_bounds__(256) void pe_final(const float* __restrict__ partial,
                                                float* __restrict__ out)
{
    __shared__ double sred[256];
    const int tid = threadIdx.x;
    double s = 0.0;
    for (int i = tid; i < NWAVES; i += 256) s += (double)partial[i];
    sred[tid] = s;
    __syncthreads();
    for (int k = 128; k > 0; k >>= 1) {
        if (tid < k) sred[tid] += sred[tid+k];
        __syncthreads();
    }
    if (tid == 0) out[0] = (float)(1.0 / (sred[0] + 1.0));
}

extern "C" void kernel_launch(void* const* d_in, const int* in_sizes, int n_in,
                              void* d_out, int out_size, void* d_ws, size_t ws_size,
                              hipStream_t stream) {
    const float* lm = (const float*)d_in[0];
    const float* re = (const float*)d_in[1];
    const float* im = (const float*)d_in[2];
    const float* S  = (const float*)d_in[3];
    float* partial = (float*)d_ws;   // NWAVES floats = 32 KB scratch
    pe_main<<<GRID, BLK, 0, stream>>>(lm, re, im, S, partial);
    pe_final<<<1, 256, 0, stream>>>(partial, (float*)d_out);
}